// Round 5
// baseline (5546.827 us; speedup 1.0000x reference)
//
#include <hip/hip_runtime.h>
#include <math.h>

#define NNODES 100000
#define NEDGES 3200000
#define F 128
#define NPB 128
#define NB 782        // ceil(100000/128)
#define CAP 5376      // mean 4092, sigma 64 -> +20 sigma
#define T2 4096

typedef __attribute__((ext_vector_type(8))) short short8;
typedef __attribute__((ext_vector_type(4))) float f32x4;

__device__ __forceinline__ unsigned short f2bf(float f) {
    unsigned u = __float_as_uint(f);
    unsigned r = u + 0x7fff + ((u >> 16) & 1);
    return (unsigned short)(r >> 16);
}
__device__ __forceinline__ float bflo(unsigned u) { return __uint_as_float(u << 16); }
__device__ __forceinline__ float bfhi(unsigned u) { return __uint_as_float(u & 0xffff0000u); }

// ---------------- cursor init ----------------

__global__ void init_cursors_kernel(int* __restrict__ dcur, int* __restrict__ scur) {
    int b = blockIdx.x * 256 + threadIdx.x;
    if (b < NB) { dcur[b] = b * CAP; scur[b] = b * CAP; }
}

// ---------------- dual binning: dst-keyed packed edges + src-keyed local ids ----------------

__global__ __launch_bounds__(256) void dual_bin_kernel(const int* __restrict__ src,
                                                       const int* __restrict__ dst,
                                                       int* __restrict__ dcur,
                                                       int* __restrict__ scur,
                                                       unsigned* __restrict__ epk,
                                                       unsigned char* __restrict__ esl) {
    __shared__ unsigned pk[T2];
    __shared__ unsigned char sl[T2];
    __shared__ unsigned short db[T2], sb[T2];
    __shared__ int dh[NB], dbase[NB], dlc[NB];
    __shared__ int sh[NB], sbase[NB], slc[NB];
    int t = threadIdx.x;
    for (int i = t; i < NB; i += 256) { dh[i] = 0; dlc[i] = 0; sh[i] = 0; slc[i] = 0; }
    __syncthreads();
    int e0 = blockIdx.x * T2;
    int n = min(T2, NEDGES - e0);
    for (int i = t; i < n; i += 256) {
        int s = src[e0 + i], d = dst[e0 + i];
        int bd = d >> 7, bs = s >> 7;
        pk[i] = (unsigned)s | ((unsigned)(d & 127) << 17);
        sl[i] = (unsigned char)(s & 127);
        db[i] = (unsigned short)bd;
        sb[i] = (unsigned short)bs;
        atomicAdd(&dh[bd], 1);
        atomicAdd(&sh[bs], 1);
    }
    __syncthreads();
    for (int b = t; b < NB; b += 256) {
        if (dh[b]) dbase[b] = atomicAdd(&dcur[b], dh[b]);
        if (sh[b]) sbase[b] = atomicAdd(&scur[b], sh[b]);
    }
    __syncthreads();
    for (int i = t; i < n; i += 256) {
        int b = db[i];
        epk[dbase[b] + atomicAdd(&dlc[b], 1)] = pk[i];
    }
    for (int i = t; i < n; i += 256) {
        int b = sb[i];
        esl[sbase[b] + atomicAdd(&slc[b], 1)] = sl[i];
    }
}

// ---------------- out-degree -> out_norm ----------------

__global__ __launch_bounds__(256) void src_hist_kernel(const unsigned char* __restrict__ esl,
                                                       const int* __restrict__ scur,
                                                       float* __restrict__ out_norm) {
    __shared__ int cnt[NPB];
    int t = threadIdx.x, b = blockIdx.x;
    if (t < NPB) cnt[t] = 0;
    __syncthreads();
    int e0 = b * CAP, e1 = scur[b];
    for (int i = e0 + t; i < e1; i += 256) atomicAdd(&cnt[esl[i]], 1);
    __syncthreads();
    int node = b * NPB + t;
    if (t < NPB && node < NNODES) out_norm[node] = rsqrtf((float)max(cnt[t], 1));
}

// ---------------- in-degree -> in_norm ----------------

__global__ __launch_bounds__(256) void dst_hist_kernel(const unsigned* __restrict__ epk,
                                                       const int* __restrict__ dcur,
                                                       float* __restrict__ in_norm) {
    __shared__ int cnt[NPB];
    int t = threadIdx.x, b = blockIdx.x;
    if (t < NPB) cnt[t] = 0;
    __syncthreads();
    int e0 = b * CAP, e1 = dcur[b];
    for (int i = e0 + t; i < e1; i += 256) atomicAdd(&cnt[epk[i] >> 17], 1);
    __syncthreads();
    int node = b * NPB + t;
    if (t < NPB && node < NNODES) in_norm[node] = rsqrtf((float)max(cnt[t], 1));
}

// ---------------- x * out_norm -> bf16, permuted pairs: hs[row*64+l] = (f_l, f_{l+64}) ----------------

__global__ __launch_bounds__(256) void scale_to_bf16_kernel(const float* __restrict__ x,
                                                            const float* __restrict__ out_norm,
                                                            unsigned* __restrict__ hs) {
    int tid = blockIdx.x * 256 + threadIdx.x;
    if (tid >= NNODES * 64) return;
    int row = tid >> 6, l = tid & 63;
    float nrm = out_norm[row];
    float a = x[(size_t)row * F + l] * nrm;
    float b = x[(size_t)row * F + l + 64] * nrm;
    hs[tid] = (unsigned)f2bf(a) | ((unsigned)f2bf(b) << 16);
}

// ---------------- pack all 4 weight matrices into MFMA B-fragments ----------------
// Bp[(c*4+s)*64+lane] = W[s*32+(lane>>4)*8+j][c*16+(lane&15)]

__global__ void pack_all_kernel(const float* __restrict__ W1, const float* __restrict__ W2,
                                const float* __restrict__ Wm1, const float* __restrict__ Wm2,
                                short8* __restrict__ Wp) {
    int idx = blockIdx.x * 256 + threadIdx.x;
    if (idx >= 7168) return;
    const float* W; int ncol, base;
    if (idx < 2048)      { W = W1;  ncol = 128; base = 0; }
    else if (idx < 4096) { W = W2;  ncol = 128; base = 2048; }
    else if (idx < 6144) { W = Wm1; ncol = 128; base = 4096; }
    else                 { W = Wm2; ncol = 64;  base = 6144; }
    int li = idx - base;
    int lane = li & 63, s = (li >> 6) & 3, c = li >> 8;
    int nn = c * 16 + (lane & 15);
    int k0 = s * 32 + (lane >> 4) * 8;
    short8 v;
#pragma unroll
    for (int j = 0; j < 8; j++) v[j] = (short)f2bf(W[(size_t)(k0 + j) * ncol + nn]);
    Wp[idx] = v;
}

// ---------------- fused aggregate (edge-parallel, LDS fp32) + GEMM (+MLP) ----------------
// MODE 1: conv1 — relu(agg@W+b)*out_norm -> bf16 permuted pairs
// MODE 2: conv2+MLP — sigmoid(relu(relu(agg@W+b)@Wm1+bm1)@Wm2+bm2) -> fp32 out

template <int MODE>
__global__ __launch_bounds__(512) void agg_fused_kernel(const unsigned* __restrict__ hs,
                                                        const unsigned* __restrict__ epk,
                                                        const int* __restrict__ dcur,
                                                        const float* __restrict__ in_norm,
                                                        const short8* __restrict__ WpA,
                                                        const float* __restrict__ biasA,
                                                        const float* __restrict__ out_norm,
                                                        const short8* __restrict__ Wp1,
                                                        const float* __restrict__ bm1,
                                                        const short8* __restrict__ Wp2,
                                                        const float* __restrict__ bm2,
                                                        void* __restrict__ Cout) {
    __shared__ float acc[NPB * 132];   // stride 132: ds_add banks 2-way (free)
    int t = threadIdx.x;
    int w = t >> 6, lane = t & 63;
    int b = blockIdx.x;

    for (int i = t; i < NPB * 132; i += 512) acc[i] = 0.f;
    __syncthreads();

    // ---- phase B: edge-parallel accumulate, 8 edges in flight per wave ----
    int e0 = b * CAP, e1 = dcur[b];
    int e = e0 + w * 8;
    for (; e + 8 <= e1; e += 64) {
        unsigned pk[8];
#pragma unroll
        for (int j = 0; j < 8; j++) pk[j] = epk[e + j];
        unsigned val[8];
#pragma unroll
        for (int j = 0; j < 8; j++) val[j] = hs[(size_t)(pk[j] & 0x1FFFF) * 64 + lane];
#pragma unroll
        for (int j = 0; j < 8; j++) {
            int dl = pk[j] >> 17;
            atomicAdd(&acc[dl * 132 + lane], bflo(val[j]));
            atomicAdd(&acc[dl * 132 + 64 + lane], bfhi(val[j]));
        }
    }
    if (e < e1) {
        int n = e1 - e;
        for (int j = 0; j < n; j++) {
            unsigned p = epk[e + j];
            unsigned v = hs[(size_t)(p & 0x1FFFF) * 64 + lane];
            int dl = p >> 17;
            atomicAdd(&acc[dl * 132 + lane], bflo(v));
            atomicAdd(&acc[dl * 132 + 64 + lane], bfhi(v));
        }
    }
    __syncthreads();

    // ---- phase D: GEMM from LDS (wave-private 16-row tile) ----
    int m = lane & 15, quad = lane >> 4;
    int lrow = w * 16 + m;
    int grow_a = b * NPB + lrow;
    float innA = (grow_a < NNODES) ? in_norm[grow_a] : 0.f;
    short8 af[4];
#pragma unroll
    for (int s = 0; s < 4; s++) {
        const float* p = &acc[lrow * 132 + s * 32 + quad * 8];
        short8 v;
#pragma unroll
        for (int j = 0; j < 8; j++) v[j] = (short)f2bf(p[j] * innA);
        af[s] = v;
    }
    f32x4 cc[8];
#pragma unroll
    for (int c = 0; c < 8; c++) {
        f32x4 a = {0.f, 0.f, 0.f, 0.f};
#pragma unroll
        for (int s = 0; s < 4; s++)
            a = __builtin_amdgcn_mfma_f32_16x16x32_bf16(af[s], WpA[(c * 4 + s) * 64 + lane], a, 0, 0, 0);
        cc[c] = a;
    }
    int grow0 = b * NPB + w * 16 + quad * 4;

    if (MODE == 1) {
        float nrm[4];
#pragma unroll
        for (int r = 0; r < 4; r++) nrm[r] = (grow0 + r < NNODES) ? out_norm[grow0 + r] : 0.f;
#pragma unroll
        for (int c = 0; c < 4; c++) {
            float bL = biasA[c * 16 + m], bH = biasA[(c + 4) * 16 + m];
#pragma unroll
            for (int r = 0; r < 4; r++) {
                int grow = grow0 + r;
                if (grow < NNODES) {
                    float vL = fmaxf(cc[c][r] + bL, 0.f) * nrm[r];
                    float vH = fmaxf(cc[c + 4][r] + bH, 0.f) * nrm[r];
                    ((unsigned*)Cout)[(size_t)grow * 64 + c * 16 + m] =
                        (unsigned)f2bf(vL) | ((unsigned)f2bf(vH) << 16);
                }
            }
        }
    } else {
        // wave-private LDS tile aliasing this wave's acc rows (already consumed)
        unsigned short* h2 = (unsigned short*)&acc[w * 16 * 132];
#pragma unroll
        for (int c = 0; c < 8; c++) {
            float bc = biasA[c * 16 + m];
#pragma unroll
            for (int r = 0; r < 4; r++)
                h2[(quad * 4 + r) * 136 + c * 16 + m] = f2bf(fmaxf(cc[c][r] + bc, 0.f));
        }
        short8 a2[4];
#pragma unroll
        for (int s = 0; s < 4; s++)
            a2[s] = *(const short8*)&h2[m * 136 + s * 32 + quad * 8];
        f32x4 dd[8];
#pragma unroll
        for (int c = 0; c < 8; c++) {
            f32x4 a = {0.f, 0.f, 0.f, 0.f};
#pragma unroll
            for (int s = 0; s < 4; s++)
                a = __builtin_amdgcn_mfma_f32_16x16x32_bf16(a2[s], Wp1[(c * 4 + s) * 64 + lane], a, 0, 0, 0);
            dd[c] = a;
        }
#pragma unroll
        for (int c = 0; c < 8; c++) {
            float bc = bm1[c * 16 + m];
#pragma unroll
            for (int r = 0; r < 4; r++)
                h2[(quad * 4 + r) * 136 + c * 16 + m] = f2bf(fmaxf(dd[c][r] + bc, 0.f));
        }
        short8 a3[4];
#pragma unroll
        for (int s = 0; s < 4; s++)
            a3[s] = *(const short8*)&h2[m * 136 + s * 32 + quad * 8];
#pragma unroll
        for (int c2 = 0; c2 < 4; c2++) {
            f32x4 a = {0.f, 0.f, 0.f, 0.f};
#pragma unroll
            for (int s = 0; s < 4; s++)
                a = __builtin_amdgcn_mfma_f32_16x16x32_bf16(a3[s], Wp2[(c2 * 4 + s) * 64 + lane], a, 0, 0, 0);
            float bc = bm2[c2 * 16 + m];
#pragma unroll
            for (int r = 0; r < 4; r++) {
                int grow = grow0 + r;
                if (grow < NNODES)
                    ((float*)Cout)[(size_t)grow * 64 + c2 * 16 + m] =
                        1.f / (1.f + __expf(-(a[r] + bc)));
            }
        }
    }
}

// ---------------- launch ----------------

extern "C" void kernel_launch(void* const* d_in, const int* in_sizes, int n_in,
                              void* d_out, int out_size, void* d_ws, size_t ws_size,
                              hipStream_t stream) {
    const float* x   = (const float*)d_in[0];
    const int* src   = (const int*)d_in[1];
    const int* dst   = (const int*)d_in[2];
    const float* W1  = (const float*)d_in[3];
    const float* b1  = (const float*)d_in[4];
    const float* W2  = (const float*)d_in[5];
    const float* b2  = (const float*)d_in[6];
    const float* Wm1 = (const float*)d_in[7];
    const float* bm1 = (const float*)d_in[8];
    const float* Wm2 = (const float*)d_in[9];
    const float* bm2 = (const float*)d_in[10];
    float* out = (float*)d_out;

    char* w = (char*)d_ws;
    int* dcur           = (int*)w;   w += (size_t)(NB + 4) * 4;
    int* scur           = (int*)w;   w += (size_t)(NB + 4) * 4;
    float* out_norm     = (float*)w; w += (size_t)NNODES * 4;
    float* in_norm      = (float*)w; w += (size_t)NNODES * 4;
    unsigned* epk       = (unsigned*)w; w += (size_t)NB * CAP * 4;
    unsigned char* esl  = (unsigned char*)w; w += (size_t)NB * CAP;
    short8* Wp          = (short8*)w; w += (size_t)7168 * 16;
    unsigned* bufX      = (unsigned*)w; w += (size_t)NNODES * 64 * 4;
    unsigned* bufY      = (unsigned*)w; w += (size_t)NNODES * 64 * 4;

    init_cursors_kernel<<<(NB + 255) / 256, 256, 0, stream>>>(dcur, scur);
    dual_bin_kernel<<<(NEDGES + T2 - 1) / T2, 256, 0, stream>>>(src, dst, dcur, scur, epk, esl);
    src_hist_kernel<<<NB, 256, 0, stream>>>(esl, scur, out_norm);
    dst_hist_kernel<<<NB, 256, 0, stream>>>(epk, dcur, in_norm);
    scale_to_bf16_kernel<<<(NNODES * 64 + 255) / 256, 256, 0, stream>>>(x, out_norm, bufX);
    pack_all_kernel<<<28, 256, 0, stream>>>(W1, W2, Wm1, Wm2, Wp);

    agg_fused_kernel<1><<<NB, 512, 0, stream>>>(bufX, epk, dcur, in_norm, Wp, b1, out_norm,
                                                nullptr, nullptr, nullptr, nullptr, bufY);
    agg_fused_kernel<2><<<NB, 512, 0, stream>>>(bufY, epk, dcur, in_norm, Wp + 2048, b2, nullptr,
                                                Wp + 4096, bm1, Wp + 6144, bm2, out);
}

// Round 6
// 567.604 us; speedup vs baseline: 9.7724x; 9.7724x over previous
//
#include <hip/hip_runtime.h>
#include <math.h>

#define NNODES 100000
#define NEDGES 3200000
#define F 128
#define NPB 512
#define NB ((NNODES + NPB - 1) / NPB)   // 196 buckets
#define CAP 20480                        // slots per bucket (mean 16326, 32 sigma margin)
#define T2 8192

typedef __attribute__((ext_vector_type(8))) short short8;
typedef __attribute__((ext_vector_type(4))) float f32x4;

__device__ __forceinline__ unsigned short f2bf(float f) {
    unsigned u = __float_as_uint(f);
    unsigned r = u + 0x7fff + ((u >> 16) & 1);
    return (unsigned short)(r >> 16);
}
__device__ __forceinline__ float bflo(unsigned u) { return __uint_as_float(u << 16); }
__device__ __forceinline__ float bfhi(unsigned u) { return __uint_as_float(u & 0xffff0000u); }

// ---------------- cursor init (CAP-strided bucket bases) ----------------

__global__ void init_cursors_kernel(int* __restrict__ dcur, int* __restrict__ scur) {
    int b = blockIdx.x * 256 + threadIdx.x;
    if (b < NB) { dcur[b] = b * CAP; scur[b] = b * CAP; }
}

// ---------------- dual binning: one edge read -> dst-keyed + src-keyed bins ----------------

__global__ __launch_bounds__(256) void dual_bin_kernel(const int* __restrict__ src,
                                                       const int* __restrict__ dst,
                                                       int* __restrict__ dcur,
                                                       int* __restrict__ scur,
                                                       unsigned* __restrict__ epk,
                                                       unsigned short* __restrict__ esl) {
    __shared__ unsigned pk[T2];
    __shared__ unsigned short sl[T2];
    __shared__ unsigned char db[T2], sb[T2];
    __shared__ int dh[NB], dbase[NB], dlc[NB];
    __shared__ int sh[NB], sbase[NB], slc[NB];
    int t = threadIdx.x;
    for (int i = t; i < NB; i += 256) { dh[i] = 0; dlc[i] = 0; sh[i] = 0; slc[i] = 0; }
    __syncthreads();
    int e0 = blockIdx.x * T2;
    int n = min(T2, NEDGES - e0);
    for (int i = t; i < n; i += 256) {
        int s = src[e0 + i], d = dst[e0 + i];
        int bd = d >> 9, bs = s >> 9;
        pk[i] = (unsigned)s | ((unsigned)(d & 511) << 17);
        sl[i] = (unsigned short)(s & 511);
        db[i] = (unsigned char)bd;
        sb[i] = (unsigned char)bs;
        atomicAdd(&dh[bd], 1);
        atomicAdd(&sh[bs], 1);
    }
    __syncthreads();
    for (int b = t; b < NB; b += 256) {
        if (dh[b]) dbase[b] = atomicAdd(&dcur[b], dh[b]);
        if (sh[b]) sbase[b] = atomicAdd(&scur[b], sh[b]);
    }
    __syncthreads();
    for (int i = t; i < n; i += 256) {
        int b = db[i];
        epk[dbase[b] + atomicAdd(&dlc[b], 1)] = pk[i];
    }
    for (int i = t; i < n; i += 256) {
        int b = sb[i];
        esl[sbase[b] + atomicAdd(&slc[b], 1)] = sl[i];
    }
}

// ---------------- out-degree -> out_norm (per-bucket LDS histogram) ----------------

__global__ __launch_bounds__(512) void src_hist_kernel(const unsigned short* __restrict__ esl,
                                                       const int* __restrict__ scur,
                                                       float* __restrict__ out_norm) {
    __shared__ int cnt[NPB];
    int t = threadIdx.x, b = blockIdx.x;
    cnt[t] = 0;
    __syncthreads();
    int e0 = b * CAP, e1 = scur[b];
    for (int i = e0 + t; i < e1; i += 512) atomicAdd(&cnt[esl[i]], 1);
    __syncthreads();
    int node = b * NPB + t;
    if (node < NNODES) out_norm[node] = rsqrtf((float)max(cnt[t], 1));
}

// ---------------- per-bucket fine CSR + in_norm (all-LDS cursors) ----------------

__global__ __launch_bounds__(512) void bucket_csr_kernel(const unsigned* __restrict__ epk,
                                                         const int* __restrict__ dcur,
                                                         int2* __restrict__ row_span,
                                                         float* __restrict__ in_norm,
                                                         int* __restrict__ csr_src) {
    __shared__ int hist[NPB], off[NPB], lcur[NPB];
    int t = threadIdx.x, b = blockIdx.x;
    hist[t] = 0; lcur[t] = 0;
    __syncthreads();
    int e0 = b * CAP, e1 = dcur[b];
    for (int i = e0 + t; i < e1; i += 512)
        atomicAdd(&hist[epk[i] >> 17], 1);
    __syncthreads();
    int h = hist[t];
    off[t] = h;
    __syncthreads();
    for (int d = 1; d < NPB; d <<= 1) {
        int u = (t >= d) ? off[t - d] : 0;
        __syncthreads();
        off[t] += u;
        __syncthreads();
    }
    int excl = off[t] - h;
    int node = b * NPB + t;
    if (node < NNODES) {
        row_span[node] = make_int2(e0 + excl, e0 + excl + h);
        in_norm[node] = rsqrtf((float)max(h, 1));
    }
    __syncthreads();
    off[t] = excl;
    __syncthreads();
    for (int i = e0 + t; i < e1; i += 512) {
        unsigned p = epk[i];
        int dl = p >> 17;
        csr_src[e0 + off[dl] + atomicAdd(&lcur[dl], 1)] = (int)(p & 0x1FFFF);
    }
}

// ---------------- x * out_norm -> bf16 (linear row-major pairs) ----------------

__global__ __launch_bounds__(256) void scale_to_bf16_kernel(const float* __restrict__ x,
                                                            const float* __restrict__ out_norm,
                                                            uint2* __restrict__ hs) {
    int tid = blockIdx.x * 256 + threadIdx.x;
    if (tid >= NNODES * 32) return;
    int row = tid >> 5, q = tid & 31;
    float nrm = out_norm[row];
    float4 v = *(const float4*)(x + (size_t)row * F + q * 4);
    uint2 o;
    o.x = (unsigned)f2bf(v.x * nrm) | ((unsigned)f2bf(v.y * nrm) << 16);
    o.y = (unsigned)f2bf(v.z * nrm) | ((unsigned)f2bf(v.w * nrm) << 16);
    hs[(size_t)row * 32 + q] = o;
}

// ---------------- pack all 4 weight matrices into MFMA B-fragments ----------------
// Bp[(c*4+s)*64+lane] = W[s*32+(lane>>4)*8+j][c*16+(lane&15)]

__global__ void pack_all_kernel(const float* __restrict__ W1, const float* __restrict__ W2,
                                const float* __restrict__ Wm1, const float* __restrict__ Wm2,
                                short8* __restrict__ Wp) {
    int idx = blockIdx.x * 256 + threadIdx.x;
    if (idx >= 7168) return;
    const float* W; int ncol, base;
    if (idx < 2048)      { W = W1;  ncol = 128; base = 0; }
    else if (idx < 4096) { W = W2;  ncol = 128; base = 2048; }
    else if (idx < 6144) { W = Wm1; ncol = 128; base = 4096; }
    else                 { W = Wm2; ncol = 64;  base = 6144; }
    int li = idx - base;
    int lane = li & 63, s = (li >> 6) & 3, c = li >> 8;
    int nn = c * 16 + (lane & 15);
    int k0 = s * 32 + (lane >> 4) * 8;
    short8 v;
#pragma unroll
    for (int j = 0; j < 8; j++) v[j] = (short)f2bf(W[(size_t)(k0 + j) * ncol + nn]);
    Wp[idx] = v;
}

// ---------------- aggregation: one wave per node, 8 gathers in flight ----------------
// lane l holds feats (2l, 2l+1) as one uint (2 bf16); fp32 accumulate.

__global__ __launch_bounds__(256) void aggregate_kernel(const unsigned* __restrict__ hs,
                                                        const int2* __restrict__ row_span,
                                                        const int* __restrict__ csr_src,
                                                        const float* __restrict__ in_norm,
                                                        unsigned* __restrict__ outv) {
    int wave = threadIdx.x >> 6;
    int lane = threadIdx.x & 63;
    int node = blockIdx.x * 4 + wave;
    if (node >= NNODES) return;
    int2 sp = row_span[node];
    int beg = sp.x, end = sp.y;
    float ax = 0.f, ay = 0.f;
    int j = beg;
    for (; j + 8 <= end; j += 8) {
        int s0 = csr_src[j],     s1 = csr_src[j + 1], s2 = csr_src[j + 2], s3 = csr_src[j + 3];
        int s4 = csr_src[j + 4], s5 = csr_src[j + 5], s6 = csr_src[j + 6], s7 = csr_src[j + 7];
        unsigned u0 = hs[(size_t)s0 * 64 + lane];
        unsigned u1 = hs[(size_t)s1 * 64 + lane];
        unsigned u2 = hs[(size_t)s2 * 64 + lane];
        unsigned u3 = hs[(size_t)s3 * 64 + lane];
        unsigned u4 = hs[(size_t)s4 * 64 + lane];
        unsigned u5 = hs[(size_t)s5 * 64 + lane];
        unsigned u6 = hs[(size_t)s6 * 64 + lane];
        unsigned u7 = hs[(size_t)s7 * 64 + lane];
        ax += bflo(u0) + bflo(u1) + bflo(u2) + bflo(u3)
            + bflo(u4) + bflo(u5) + bflo(u6) + bflo(u7);
        ay += bfhi(u0) + bfhi(u1) + bfhi(u2) + bfhi(u3)
            + bfhi(u4) + bfhi(u5) + bfhi(u6) + bfhi(u7);
    }
    for (; j < end; j++) {
        unsigned u0 = hs[(size_t)csr_src[j] * 64 + lane];
        ax += bflo(u0);
        ay += bfhi(u0);
    }
    float inn = in_norm[node];
    outv[(size_t)node * 64 + lane] =
        (unsigned)f2bf(ax * inn) | ((unsigned)f2bf(ay * inn) << 16);
}

// ---------------- MFMA GEMM (conv layers): relu(A@W+b), optional *out_norm ----------------

template <int SCALE>
__global__ __launch_bounds__(256) void gemm_mfma_kernel(const unsigned short* __restrict__ A,
                                                        const short8* __restrict__ Bp,
                                                        const float* __restrict__ bias,
                                                        const float* __restrict__ out_norm,
                                                        unsigned short* __restrict__ Cout, int nrows) {
    int w = threadIdx.x >> 6, lane = threadIdx.x & 63;
    int m = lane & 15, quad = lane >> 4;
    int row0 = blockIdx.x * 64 + w * 16;

    int arow = min(row0 + m, nrows - 1);
    short8 afrag[4];
#pragma unroll
    for (int s = 0; s < 4; s++)
        afrag[s] = *(const short8*)(A + (size_t)arow * F + s * 32 + quad * 8);

    int baseRow = row0 + quad * 4;
    float nrm[4];
    if (SCALE) {
#pragma unroll
        for (int r = 0; r < 4; r++) nrm[r] = out_norm[min(baseRow + r, nrows - 1)];
    }

#pragma unroll
    for (int c = 0; c < 8; c++) {
        f32x4 acc = {0.f, 0.f, 0.f, 0.f};
#pragma unroll
        for (int s = 0; s < 4; s++) {
            short8 b = Bp[(c * 4 + s) * 64 + lane];
            acc = __builtin_amdgcn_mfma_f32_16x16x32_bf16(afrag[s], b, acc, 0, 0, 0);
        }
        float bc = bias[c * 16 + m];
#pragma unroll
        for (int r = 0; r < 4; r++) {
            int row = baseRow + r;
            if (row < nrows) {
                float v = fmaxf(acc[r] + bc, 0.f);
                if (SCALE) v *= nrm[r];
                Cout[(size_t)row * F + c * 16 + m] = f2bf(v);
            }
        }
    }
}

// ---------------- fused MLP head: sigmoid(relu(A@Wm1+bm1)@Wm2+bm2) ----------------

__global__ __launch_bounds__(256) void mlp_fused_kernel(const unsigned short* __restrict__ A,
                                                        const short8* __restrict__ Bp1,
                                                        const float* __restrict__ bm1,
                                                        const short8* __restrict__ Bp2,
                                                        const float* __restrict__ bm2,
                                                        float* __restrict__ out, int nrows) {
    __shared__ unsigned short h3[4][16][136];   // +8 pad: break bank conflicts
    int w = threadIdx.x >> 6, lane = threadIdx.x & 63;
    int m = lane & 15, quad = lane >> 4;
    int row0 = blockIdx.x * 64 + w * 16;

    int arow = min(row0 + m, nrows - 1);
    short8 afrag[4];
#pragma unroll
    for (int s = 0; s < 4; s++)
        afrag[s] = *(const short8*)(A + (size_t)arow * F + s * 32 + quad * 8);

#pragma unroll
    for (int c = 0; c < 8; c++) {
        f32x4 acc = {0.f, 0.f, 0.f, 0.f};
#pragma unroll
        for (int s = 0; s < 4; s++) {
            short8 b = Bp1[(c * 4 + s) * 64 + lane];
            acc = __builtin_amdgcn_mfma_f32_16x16x32_bf16(afrag[s], b, acc, 0, 0, 0);
        }
        float bc = bm1[c * 16 + m];
#pragma unroll
        for (int r = 0; r < 4; r++)
            h3[w][quad * 4 + r][c * 16 + m] = f2bf(fmaxf(acc[r] + bc, 0.f));
    }
    __syncthreads();

    short8 a2[4];
#pragma unroll
    for (int s = 0; s < 4; s++)
        a2[s] = *(const short8*)(&h3[w][m][s * 32 + quad * 8]);

    int baseRow = row0 + quad * 4;
#pragma unroll
    for (int c2 = 0; c2 < 4; c2++) {
        f32x4 acc = {0.f, 0.f, 0.f, 0.f};
#pragma unroll
        for (int s = 0; s < 4; s++) {
            short8 b = Bp2[(c2 * 4 + s) * 64 + lane];
            acc = __builtin_amdgcn_mfma_f32_16x16x32_bf16(a2[s], b, acc, 0, 0, 0);
        }
        float bc = bm2[c2 * 16 + m];
#pragma unroll
        for (int r = 0; r < 4; r++) {
            int row = baseRow + r;
            if (row < nrows)
                out[(size_t)row * 64 + c2 * 16 + m] = 1.f / (1.f + __expf(-(acc[r] + bc)));
        }
    }
}

// ---------------- launch ----------------

extern "C" void kernel_launch(void* const* d_in, const int* in_sizes, int n_in,
                              void* d_out, int out_size, void* d_ws, size_t ws_size,
                              hipStream_t stream) {
    const float* x   = (const float*)d_in[0];
    const int* src   = (const int*)d_in[1];
    const int* dst   = (const int*)d_in[2];
    const float* W1  = (const float*)d_in[3];
    const float* b1  = (const float*)d_in[4];
    const float* W2  = (const float*)d_in[5];
    const float* b2  = (const float*)d_in[6];
    const float* Wm1 = (const float*)d_in[7];
    const float* bm1 = (const float*)d_in[8];
    const float* Wm2 = (const float*)d_in[9];
    const float* bm2 = (const float*)d_in[10];
    float* out = (float*)d_out;

    char* w = (char*)d_ws;
    int* dcur          = (int*)w;   w += (size_t)(NB + 4) * 4;
    int* scur          = (int*)w;   w += (size_t)(NB + 4) * 4;
    float* out_norm    = (float*)w; w += (size_t)NNODES * 4;
    float* in_norm     = (float*)w; w += (size_t)NNODES * 4;
    int2* row_span     = (int2*)w;  w += (size_t)NNODES * 8;
    int* csr_src       = (int*)w;   w += (size_t)NB * CAP * 4;
    unsigned* epk      = (unsigned*)w; w += (size_t)NB * CAP * 4;
    unsigned short* esl= (unsigned short*)w; w += (size_t)NB * CAP * 2;
    short8* Wp         = (short8*)w; w += (size_t)7168 * 16;
    unsigned* bufX     = (unsigned*)w; w += (size_t)NNODES * 64 * 4;
    unsigned* bufY     = (unsigned*)w; w += (size_t)NNODES * 64 * 4;

    init_cursors_kernel<<<1, 256, 0, stream>>>(dcur, scur);
    dual_bin_kernel<<<(NEDGES + T2 - 1) / T2, 256, 0, stream>>>(src, dst, dcur, scur, epk, esl);
    src_hist_kernel<<<NB, 512, 0, stream>>>(esl, scur, out_norm);
    bucket_csr_kernel<<<NB, 512, 0, stream>>>(epk, dcur, row_span, in_norm, csr_src);
    scale_to_bf16_kernel<<<(NNODES * 32 + 255) / 256, 256, 0, stream>>>(x, out_norm, (uint2*)bufX);
    pack_all_kernel<<<28, 256, 0, stream>>>(W1, W2, Wm1, Wm2, Wp);

    const int aggGrid = (NNODES + 3) / 4;
    const int gemmGrid = (NNODES + 63) / 64;

    aggregate_kernel<<<aggGrid, 256, 0, stream>>>(bufX, row_span, csr_src, in_norm, bufY);
    gemm_mfma_kernel<1><<<gemmGrid, 256, 0, stream>>>((const unsigned short*)bufY, Wp, b1, out_norm,
                                                      (unsigned short*)bufX, NNODES);
    aggregate_kernel<<<aggGrid, 256, 0, stream>>>(bufX, row_span, csr_src, in_norm, bufY);
    gemm_mfma_kernel<0><<<gemmGrid, 256, 0, stream>>>((const unsigned short*)bufY, Wp + 2048, b2, out_norm,
                                                      (unsigned short*)bufX, NNODES);
    mlp_fused_kernel<<<gemmGrid, 256, 0, stream>>>((const unsigned short*)bufX, Wp + 4096, bm1,
                                                   Wp + 6144, bm2, out, NNODES);
}